// Round 8
// baseline (26.593 us; speedup 1.0000x reference)
//
#include <hip/hip_runtime.h>
#include <math.h>

#define TPB 512
#define WAVES 8
#define RAYS_PB 256      // rays per block
#define RPT 4            // rays per thread (RAYS_PB / 64)
#define MAXPTS 2048      // points staged in LDS per chunk (f16x4 -> 16 KB)

typedef _Float16 h2 __attribute__((ext_vector_type(2)));

__device__ __forceinline__ h2 bch2(unsigned int u) {
    union { unsigned int u; h2 h; } v; v.u = u; return v.h;
}
__device__ __forceinline__ unsigned int bcu(h2 h) {
    union { h2 h; unsigned int u; } v; v.h = h; return v.u;
}

// f32-accumulating f16 dot2: s = a.x*b.x + a.y*b.y + c
__device__ __forceinline__ float dot2acc(h2 a, h2 b, float c) {
#if __has_builtin(__builtin_amdgcn_fdot2)
    return __builtin_amdgcn_fdot2(a, b, c, false);
#else
    // fma_mix-friendly form: f16 operand widened inside fma
    return fmaf((float)a[0], (float)b[0], fmaf((float)a[1], (float)b[1], c));
#endif
}

// ---------------------------------------------------------------------------
// Fused main: grid = (ceil(M/256), B), block = 512 (8 waves).
// Each block: 256 rays vs ALL N points.
//  - stages pc into LDS as f16x4 (qx,qy,qz,-0.5|q|^2): 2 points / 16B entry
//  - computes the COMPLETE maxdist locally (f32, exact)
//  - wave w scans its N/8 point chunk for all 256 rays (4 rays/thread in
//    registers); ONE ds_read_b128 delivers TWO points; v_dot2_f32_f16 +
//    v_max3_f32 inner loop
//  - cross-wave max combine in LDS, masked sum -> ONE float2 per block.
// Deterministic: fixed-order in-block reductions, no atomics.
//   min_n d2 = pn - 2 * max_n (p.q - 0.5|q|^2)
// ---------------------------------------------------------------------------
__global__ __launch_bounds__(TPB) void chamfer_main(
    const float* __restrict__ c, const float* __restrict__ depth,
    const float* __restrict__ pc, float2* __restrict__ partial,
    int res, int M, int N)
{
    __shared__ uint4 spair[MAXPTS / 2];       // 16 KB: 2 packed points/entry
    __shared__ float red[WAVES][RAYS_PB];     // 8 KB
    __shared__ float smax[WAVES];
    __shared__ float bs[RPT], bc[RPT];

    int tile = blockIdx.x, b = blockIdx.y;
    int tid = threadIdx.x, w = tid >> 6, lane = tid & 63;

    const float* cb = c + b * 25;
    float fx = cb[16], sk = cb[17], cx = cb[18];
    float fy = cb[20], cy = cb[21];
    float ox = cb[3], oy = cb[7], oz = cb[11];

    // ---- ray setup: 4 rays per thread; pack p into f16 pairs for dot2 ----
    h2 pxy[RPT], pz1[RPT];
    float pn[RPT], dep[RPT], mxs[RPT];
    #pragma unroll
    for (int r = 0; r < RPT; ++r) {
        int m = tile * RAYS_PB + lane + 64 * r;
        int mm = min(m, M - 1);
        int i = mm / res, j = mm - i * res;
        float x = (j + 0.5f) / (float)res;
        float y = (i + 0.5f) / (float)res;
        float xl = (x - cx + cy * sk / fy - sk * y / fy) / fx;
        float yl = (y - cy) / fy;
        float wx = cb[0] * xl + cb[1] * yl + cb[2] + cb[3];
        float wy = cb[4] * xl + cb[5] * yl + cb[6] + cb[7];
        float wz = cb[8] * xl + cb[9] * yl + cb[10] + cb[11];
        float dx = wx - ox, dy = wy - oy, dz = wz - oz;
        float nrm = fmaxf(sqrtf(dx * dx + dy * dy + dz * dz), 1e-12f);
        dx /= nrm; dy /= nrm; dz /= nrm;
        float d = depth[(size_t)b * M + mm];
        dep[r] = d;
        float px_ = fmaf(d, dx, ox);
        float py_ = fmaf(d, dy, oy);
        float pz_ = fmaf(d, dz, oz);
        pn[r] = px_ * px_ + py_ * py_ + pz_ * pz_;
        pxy[r] = (h2){(_Float16)px_, (_Float16)py_};
        pz1[r] = (h2){(_Float16)pz_, (_Float16)1.0f};
        mxs[r] = -3.4e38f;
    }

    // ---- stage + scan all N points (chunked; N<=MAXPTS -> single pass) ----
    float mdl = 0.0f;   // squared distances >= 0
    for (int n0 = 0; n0 < N; n0 += MAXPTS) {
        int kc = min(N - n0, MAXPTS);
        if (n0) __syncthreads();   // previous chunk's reads complete
        const float* src = pc + ((size_t)b * N + n0) * 3;

        // vectorized staging: 4 points / thread via 3 float4 loads
        int g4 = kc >> 2;
        const float4* s4 = (const float4*)src;
        for (int g = tid; g < g4; g += TPB) {
            float4 f0 = s4[3 * g], f1 = s4[3 * g + 1], f2 = s4[3 * g + 2];
            float qx0 = f0.x, qy0 = f0.y, qz0 = f0.z;
            float qx1 = f0.w, qy1 = f1.x, qz1 = f1.y;
            float qx2 = f1.z, qy2 = f1.w, qz2 = f2.x;
            float qx3 = f2.y, qy3 = f2.z, qz3 = f2.w;
            float qn0 = qx0*qx0 + qy0*qy0 + qz0*qz0;
            float qn1 = qx1*qx1 + qy1*qy1 + qz1*qz1;
            float qn2 = qx2*qx2 + qy2*qy2 + qz2*qz2;
            float qn3 = qx3*qx3 + qy3*qy3 + qz3*qz3;
            uint4 e0, e1;
            e0.x = bcu((h2){(_Float16)qx0, (_Float16)qy0});
            e0.y = bcu((h2){(_Float16)qz0, (_Float16)(-0.5f * qn0)});
            e0.z = bcu((h2){(_Float16)qx1, (_Float16)qy1});
            e0.w = bcu((h2){(_Float16)qz1, (_Float16)(-0.5f * qn1)});
            e1.x = bcu((h2){(_Float16)qx2, (_Float16)qy2});
            e1.y = bcu((h2){(_Float16)qz2, (_Float16)(-0.5f * qn2)});
            e1.z = bcu((h2){(_Float16)qx3, (_Float16)qy3});
            e1.w = bcu((h2){(_Float16)qz3, (_Float16)(-0.5f * qn3)});
            spair[2 * g]     = e0;
            spair[2 * g + 1] = e1;
            // maxdist partial (exact f32)
            float d0x = qx0 - ox, d0y = qy0 - oy, d0z = qz0 - oz;
            float d1x = qx1 - ox, d1y = qy1 - oy, d1z = qz1 - oz;
            float d2x = qx2 - ox, d2y = qy2 - oy, d2z = qz2 - oz;
            float d3x = qx3 - ox, d3y = qy3 - oy, d3z = qz3 - oz;
            mdl = fmaxf(mdl, fmaxf(
                fmaxf(d0x*d0x + d0y*d0y + d0z*d0z, d1x*d1x + d1y*d1y + d1z*d1z),
                fmaxf(d2x*d2x + d2y*d2y + d2z*d2z, d3x*d3x + d3y*d3y + d3z*d3z)));
        }
        // scalar tail (kc % 4)
        for (int p = (g4 << 2) + tid; p < kc; p += TPB) {
            float qx = src[3 * p], qy = src[3 * p + 1], qz = src[3 * p + 2];
            float qn = qx * qx + qy * qy + qz * qz;
            uint2 e;
            e.x = bcu((h2){(_Float16)qx, (_Float16)qy});
            e.y = bcu((h2){(_Float16)qz, (_Float16)(-0.5f * qn)});
            ((uint2*)spair)[p] = e;
            float dx = qx - ox, dy = qy - oy, dz = qz - oz;
            mdl = fmaxf(mdl, dx * dx + dy * dy + dz * dz);
        }
        __syncthreads();

        // wave w's point range (even-sized)
        int cpw = (((kc >> 1) + WAVES - 1) / WAVES) << 1;
        int s0 = min(w * cpw, kc);
        int s1 = min(s0 + cpw, kc);
        int pp0 = s0 >> 1, pp1 = s1 >> 1;
        #pragma unroll 4
        for (int kk = pp0; kk < pp1; ++kk) {
            uint4 qq = spair[kk];            // 2 points per broadcast b128
            h2 a0 = bch2(qq.x), a1 = bch2(qq.y);
            h2 b0 = bch2(qq.z), b1 = bch2(qq.w);
            #pragma unroll
            for (int r = 0; r < RPT; ++r) {
                float sa = dot2acc(pz1[r], a1, dot2acc(pxy[r], a0, 0.0f));
                float sb = dot2acc(pz1[r], b1, dot2acc(pxy[r], b0, 0.0f));
                mxs[r] = fmaxf(mxs[r], fmaxf(sa, sb));   // -> v_max3_f32
            }
        }
        if ((s1 & 1) && s1 == kc) {          // odd tail point
            uint2 qv = ((const uint2*)spair)[kc - 1];
            h2 a0 = bch2(qv.x), a1 = bch2(qv.y);
            #pragma unroll
            for (int r = 0; r < RPT; ++r) {
                float sa = dot2acc(pz1[r], a1, dot2acc(pxy[r], a0, 0.0f));
                mxs[r] = fmaxf(mxs[r], sa);
            }
        }
    }

    // ---- per-wave maxdist partial + per-ray max handoff ----
    for (int off = 32; off; off >>= 1) mdl = fmaxf(mdl, __shfl_down(mdl, off));
    if (lane == 0) smax[w] = mdl;
    #pragma unroll
    for (int r = 0; r < RPT; ++r) red[w][lane + 64 * r] = mxs[r];
    __syncthreads();

    // ---- combine: thread tid (<256) owns ray tid ----
    float s = 0.f, cnt = 0.f;
    if (tid < RAYS_PB) {
        float m2 = smax[0];
        #pragma unroll
        for (int ww = 1; ww < WAVES; ++ww) m2 = fmaxf(m2, smax[ww]);
        float thr = sqrtf(m2);

        float mx = red[0][tid];
        #pragma unroll
        for (int ww = 1; ww < WAVES; ++ww) mx = fmaxf(mx, red[ww][tid]);
        // ray tid's pn/dep live in this thread's slot r == w (static select)
        float pnk = pn[0], dk = dep[0];
        #pragma unroll
        for (int r = 1; r < RPT; ++r) if (w == r) { pnk = pn[r]; dk = dep[r]; }
        int m = tile * RAYS_PB + tid;
        if (m < M) {
            float md = fmaxf(fmaf(-2.0f, mx, pnk), 0.0f);
            if (dk < thr) { s = md; cnt = 1.0f; }
        }
    }
    for (int off = 32; off; off >>= 1) {
        s += __shfl_down(s, off);
        cnt += __shfl_down(cnt, off);
    }
    if (tid < RAYS_PB && lane == 0) { bs[w] = s; bc[w] = cnt; }
    __syncthreads();
    if (tid == 0) {
        float S = 0.f, C = 0.f;
        #pragma unroll
        for (int ww = 0; ww < RPT; ++ww) { S += bs[ww]; C += bc[ww]; }
        partial[(size_t)b * gridDim.x + blockIdx.x] = make_float2(S, C);
    }
}

// ---------------------------------------------------------------------------
// Finalize: ONE block; wave w reduces batch w's ntiles partials.
// ---------------------------------------------------------------------------
__global__ __launch_bounds__(1024) void finalize_kernel(
    const float2* __restrict__ partial, float* __restrict__ out,
    int ntiles, int B)
{
    int w = threadIdx.x >> 6, lane = threadIdx.x & 63;
    if (w >= B) return;
    float S = 0.f, C = 0.f;
    for (int i = lane; i < ntiles; i += 64) {
        float2 p = partial[(size_t)w * ntiles + i];
        S += p.x; C += p.y;
    }
    for (int off = 32; off; off >>= 1) {
        S += __shfl_down(S, off);
        C += __shfl_down(C, off);
    }
    if (lane == 0) out[w] = S / fmaxf(C, 1.0f);
}

extern "C" void kernel_launch(void* const* d_in, const int* in_sizes, int n_in,
                              void* d_out, int out_size, void* d_ws, size_t ws_size,
                              hipStream_t stream) {
    const float* c     = (const float*)d_in[0];
    const float* depth = (const float*)d_in[1];
    const float* pc    = (const float*)d_in[2];

    int B = in_sizes[0] / 25;
    int M = in_sizes[1] / B;
    int N = in_sizes[2] / (3 * B);
    int res = 1;
    while (res * res < M) ++res;

    float2* partial = (float2*)d_ws;

    int ntiles = (M + RAYS_PB - 1) / RAYS_PB;

    chamfer_main<<<dim3(ntiles, B), TPB, 0, stream>>>(c, depth, pc, partial,
                                                      res, M, N);
    finalize_kernel<<<1, B * 64, 0, stream>>>(partial, (float*)d_out,
                                              ntiles, B);
}